// Round 2
// baseline (823.031 us; speedup 1.0000x reference)
//
#include <hip/hip_runtime.h>

typedef unsigned short u16;
typedef unsigned int u32;
typedef float f32x4 __attribute__((ext_vector_type(4)));
typedef __bf16 bf16x8 __attribute__((ext_vector_type(8)));

__device__ __forceinline__ u16 f2b(float f) {
    u32 b = __builtin_bit_cast(u32, f);
    b = b + 0x7FFFu + ((b >> 16) & 1u);
    return (u16)(b >> 16);
}

// ---------------- fp32 -> bf16 convert (4 elems/thread) ----------------
__global__ __launch_bounds__(256) void k_convert(const float* __restrict__ in,
                                                 u16* __restrict__ out, int n4) {
    int i = blockIdx.x * 256 + threadIdx.x;
    if (i >= n4) return;
    f32x4 v = reinterpret_cast<const f32x4*>(in)[i];
    ushort4 o;
    o.x = f2b(v.x); o.y = f2b(v.y); o.z = f2b(v.z); o.w = f2b(v.w);
    reinterpret_cast<ushort4*>(out)[i] = o;
}

// ---------------- generic NT bf16 GEMM ----------------
// C[m,n] = scale * sum_k A[m,k]*B[n,k]  (+bias)(+relu)(+res), A,B bf16(u16), out f32 or bf16
// BM=BN=128, BK=64, 256 threads (4 waves, 2x2 of 64x64), mfma 16x16x32 bf16.
// LDS fragment-ordered: [mt 0..7][ks 0..1][lane 0..63][8 u16]; addr = ((mt*2+ks)*64+lane)*8.
// Fragment: lane l -> row = mt*16 + (l&15), k = ks*32 + (l>>4)*8 + j.
template<int BIAS /*0 none,1 col,2 row*/, int ACT, int OUTF32, int RES>
__global__ __launch_bounds__(256, 2) void gemm_nt(
    const u16* __restrict__ A, long sA,
    const u16* __restrict__ B, long sB,
    const float* __restrict__ bias,
    const float* __restrict__ res, long sRes,
    void* __restrict__ Cv, long sC,
    int ldA, int ldB, int ldC, int K, float scale)
{
    __shared__ u16 Al[8192];
    __shared__ u16 Bl[8192];
    const int tid = threadIdx.x;
    const int bz = blockIdx.z;
    const int m0 = blockIdx.y * 128;
    const int n0 = blockIdx.x * 128;
    A += (long)bz * sA;
    B += (long)bz * sB;
    const int l = tid & 63;
    const int w = tid >> 6;
    const int wr = w >> 1, wc = w & 1;

    // staging: 16B chunk (8 bf16 along k) per thread, 4 iterations (rows +32)
    const int c16 = tid & 7;     // k8 index within 64-wide k tile
    const int row0 = tid >> 3;   // 0..31
    // LDS target for (row=row0+32i, k8=c16): mt=(row0>>4)+2i, ks=c16>>2, lane=(c16&3)*16+(row0&15)
    const int la0 = (((row0 >> 4) * 2 + (c16 >> 2)) * 64 + (c16 & 3) * 16 + (row0 & 15)) * 8;

    const u16* pA = A + (long)(m0 + row0) * ldA + c16 * 8;
    const u16* pB = B + (long)(n0 + row0) * ldB + c16 * 8;

    f32x4 acc[4][4] = {};

    for (int k0 = 0; k0 < K; k0 += 64) {
        __syncthreads();
        uint4 va[4], vb[4];
        #pragma unroll
        for (int i = 0; i < 4; i++) {
            va[i] = *reinterpret_cast<const uint4*>(pA + (long)i * 32 * ldA + k0);
            vb[i] = *reinterpret_cast<const uint4*>(pB + (long)i * 32 * ldB + k0);
        }
        #pragma unroll
        for (int i = 0; i < 4; i++) {
            *reinterpret_cast<uint4*>(&Al[la0 + i * 2048]) = va[i];  // +32 rows = +2 mt = +2048 u16
            *reinterpret_cast<uint4*>(&Bl[la0 + i * 2048]) = vb[i];
        }
        __syncthreads();
        #pragma unroll
        for (int ks = 0; ks < 2; ks++) {
            bf16x8 af[4], bfr[4];
            #pragma unroll
            for (int t = 0; t < 4; t++) {
                af[t]  = *reinterpret_cast<const bf16x8*>(&Al[((wr * 4 + t) * 2 + ks) * 512 + l * 8]);
                bfr[t] = *reinterpret_cast<const bf16x8*>(&Bl[((wc * 4 + t) * 2 + ks) * 512 + l * 8]);
            }
            #pragma unroll
            for (int mt = 0; mt < 4; mt++)
                #pragma unroll
                for (int nt = 0; nt < 4; nt++)
                    acc[mt][nt] = __builtin_amdgcn_mfma_f32_16x16x32_bf16(af[mt], bfr[nt], acc[mt][nt], 0, 0, 0);
        }
    }

    // epilogue: D col=l&15, row=(l>>4)*4+reg (m89-verified layout)
    const int lr = (l >> 4) * 4;
    const int lc = l & 15;
    #pragma unroll
    for (int mt = 0; mt < 4; mt++) {
        #pragma unroll
        for (int i = 0; i < 4; i++) {
            const int row = m0 + wr * 64 + mt * 16 + lr + i;
            #pragma unroll
            for (int nt = 0; nt < 4; nt++) {
                const int col = n0 + wc * 64 + nt * 16 + lc;
                float v = acc[mt][nt][i] * scale;
                if (BIAS == 1) v += bias[col];
                if (BIAS == 2) v += bias[row];
                if (ACT) v = fmaxf(v, 0.0f);
                if (RES) v += res[(long)bz * sRes + (long)row * ldC + col];
                const long ci = (long)bz * sC + (long)row * ldC + col;
                if (OUTF32) ((float*)Cv)[ci] = v;
                else        ((u16*)Cv)[ci] = f2b(v);
            }
        }
    }
}

// ------- row softmax: 1024 f32 in -> 1024 bf16 written IN-PLACE (row stride 2048 u16) -------
__global__ __launch_bounds__(256) void k_softmax(float* __restrict__ sc) {
    __shared__ float red[8];
    const int r = blockIdx.x;
    const int t = threadIdx.x;
    const int w = t >> 6;
    float* p = sc + (long)r * 1024;
    f32x4 v = reinterpret_cast<const f32x4*>(p)[t];
    float m = fmaxf(fmaxf(v.x, v.y), fmaxf(v.z, v.w));
    #pragma unroll
    for (int d = 32; d >= 1; d >>= 1) m = fmaxf(m, __shfl_xor(m, d));
    if ((t & 63) == 0) red[w] = m;
    __syncthreads();
    m = fmaxf(fmaxf(red[0], red[1]), fmaxf(red[2], red[3]));
    f32x4 e;
    e.x = __expf(v.x - m); e.y = __expf(v.y - m);
    e.z = __expf(v.z - m); e.w = __expf(v.w - m);
    float s = e.x + e.y + e.z + e.w;
    #pragma unroll
    for (int d = 32; d >= 1; d >>= 1) s += __shfl_xor(s, d);
    if ((t & 63) == 0) red[4 + w] = s;
    __syncthreads();
    s = red[4] + red[5] + red[6] + red[7];
    const float inv = 1.0f / s;
    ushort4 o;
    o.x = f2b(e.x * inv); o.y = f2b(e.y * inv);
    o.z = f2b(e.z * inv); o.w = f2b(e.w * inv);
    // write bf16 attn row into the first 2KB of this row's own 4KB slot (no cross-row overlap)
    reinterpret_cast<ushort4*>(reinterpret_cast<u16*>(sc) + (long)r * 2048)[t] = o;
}

// ---------------- LayerNorm over D=512, one wave per row ----------------
__global__ __launch_bounds__(256) void k_layernorm(const float* __restrict__ in,
                                                   const float* __restrict__ g,
                                                   const float* __restrict__ be,
                                                   float* __restrict__ of,
                                                   u16* __restrict__ ob) {
    const int w = threadIdx.x >> 6;
    const int l = threadIdx.x & 63;
    const long row = (long)blockIdx.x * 4 + w;
    const float* p = in + row * 512;
    f32x4 v0 = *reinterpret_cast<const f32x4*>(p + l * 4);
    f32x4 v1 = *reinterpret_cast<const f32x4*>(p + 256 + l * 4);
    float s = v0.x + v0.y + v0.z + v0.w + v1.x + v1.y + v1.z + v1.w;
    float q = v0.x * v0.x + v0.y * v0.y + v0.z * v0.z + v0.w * v0.w
            + v1.x * v1.x + v1.y * v1.y + v1.z * v1.z + v1.w * v1.w;
    #pragma unroll
    for (int d = 32; d >= 1; d >>= 1) { s += __shfl_xor(s, d); q += __shfl_xor(q, d); }
    const float mean = s * (1.0f / 512.0f);
    const float var = q * (1.0f / 512.0f) - mean * mean;
    const float inv = rsqrtf(var + 1e-5f);
    f32x4 ga = *reinterpret_cast<const f32x4*>(g + l * 4);
    f32x4 gb = *reinterpret_cast<const f32x4*>(g + 256 + l * 4);
    f32x4 ba = *reinterpret_cast<const f32x4*>(be + l * 4);
    f32x4 bb = *reinterpret_cast<const f32x4*>(be + 256 + l * 4);
    f32x4 o0 = (v0 - mean) * inv * ga + ba;
    f32x4 o1 = (v1 - mean) * inv * gb + bb;
    *reinterpret_cast<f32x4*>(of + row * 512 + l * 4) = o0;
    *reinterpret_cast<f32x4*>(of + row * 512 + 256 + l * 4) = o1;
    if (ob) {
        ushort4 p0, p1;
        p0.x = f2b(o0.x); p0.y = f2b(o0.y); p0.z = f2b(o0.z); p0.w = f2b(o0.w);
        p1.x = f2b(o1.x); p1.y = f2b(o1.y); p1.z = f2b(o1.z); p1.w = f2b(o1.w);
        *reinterpret_cast<ushort4*>(ob + row * 512 + l * 4) = p0;
        *reinterpret_cast<ushort4*>(ob + row * 512 + 256 + l * 4) = p1;
    }
}

extern "C" void kernel_launch(void* const* d_in, const int* in_sizes, int n_in,
                              void* d_out, int out_size, void* d_ws, size_t ws_size,
                              hipStream_t stream) {
    const float* x   = (const float*)d_in[0];
    const float* Wq  = (const float*)d_in[1];
    const float* bq  = (const float*)d_in[2];
    const float* Wk  = (const float*)d_in[3];
    const float* bk  = (const float*)d_in[4];
    const float* Wv  = (const float*)d_in[5];
    const float* bv  = (const float*)d_in[6];
    const float* Wo  = (const float*)d_in[7];
    const float* bo  = (const float*)d_in[8];
    const float* g0  = (const float*)d_in[9];
    const float* be0 = (const float*)d_in[10];
    const float* W1  = (const float*)d_in[11];
    const float* b1  = (const float*)d_in[12];
    const float* W2  = (const float*)d_in[13];
    const float* b2  = (const float*)d_in[14];
    const float* g1  = (const float*)d_in[15];
    const float* be1 = (const float*)d_in[16];
    float* out = (float*)d_out;

    // ---- workspace layout, peak 194.0 MB (was 277.9 -> suspected ws overflow/page-fault) ----
    char* ws = (char*)d_ws;
    u16*   xb     = (u16*)(ws + 0);            // [8192,512] bf16, 8.4 MB
    u16*   Wqb    = (u16*)(ws + 8388608);      // 4 MB each
    u16*   Wkb    = (u16*)(ws + 12582912);
    u16*   Wvb    = (u16*)(ws + 16777216);
    u16*   Wob    = (u16*)(ws + 20971520);
    u16*   W1b    = (u16*)(ws + 25165824);
    u16*   W2b    = (u16*)(ws + 25690112);
    // region R1 [26214400 .. 93323264): Q -> later VT -> later hsum/hf/hb/ff1/t2
    u16*   Qb     = (u16*)(ws + 26214400);     // [8192,4096] bf16
    u16*   VTb    = Qb;                        // [8][4096,1024] bf16 (Q dead after scores)
    float* hsum   = (float*)(ws + 26214400);   // [8192,512] f32 (VT dead after PV)
    float* hf     = (float*)(ws + 42991616);
    u16*   hb     = (u16*)(ws + 59768832);
    u16*   ff1b   = (u16*)(ws + 68157440);
    float* t2     = (float*)(ws + 76546048);   // ends exactly at 93323264
    // region R2 [93323264 .. 160432128): K -> later sdpa
    u16*   Kb     = (u16*)(ws + 93323264);     // [8192,4096] bf16
    u16*   sdpab  = Kb;                        // [8][1024,4096] bf16 (K dead after scores)
    // region R3 [160432128 .. 193986560): scores f32, attn bf16 in-place (ld 2048)
    float* scores = (float*)(ws + 160432128);  // [8,1024,1024] f32
    u16*   attnb  = (u16*)scores;              // rows at stride 2048 u16

    // bf16 conversions
    k_convert<<<4096, 256, 0, stream>>>(x,  xb,  1048576);
    k_convert<<<2048, 256, 0, stream>>>(Wq, Wqb, 524288);
    k_convert<<<2048, 256, 0, stream>>>(Wk, Wkb, 524288);
    k_convert<<<2048, 256, 0, stream>>>(Wv, Wvb, 524288);
    k_convert<<<2048, 256, 0, stream>>>(Wo, Wob, 524288);
    k_convert<<<256,  256, 0, stream>>>(W1, W1b, 65536);
    k_convert<<<256,  256, 0, stream>>>(W2, W2b, 65536);

    const float scl = 0.044194173824159216f; // 1/sqrt(512)

    // Q = x·Wq^T + bq   [8192,4096]
    gemm_nt<1,0,0,0><<<dim3(32,64,1), 256, 0, stream>>>(xb,0, Wqb,0, bq, nullptr,0, Qb,0, 512,512,4096, 512, 1.0f);
    // K = x·Wk^T + bk
    gemm_nt<1,0,0,0><<<dim3(32,64,1), 256, 0, stream>>>(xb,0, Wkb,0, bk, nullptr,0, Kb,0, 512,512,4096, 512, 1.0f);
    // scores[b] = (Q[b]·K[b]^T)/sqrt(512)  f32 [8][1024,1024]
    gemm_nt<0,0,1,0><<<dim3(8,8,8), 256, 0, stream>>>(Qb,4194304, Kb,4194304, nullptr, nullptr,0, scores,1048576, 4096,4096,1024, 4096, scl);
    // attn = softmax(scores) -> bf16 in-place (row stride 2048)
    k_softmax<<<8192, 256, 0, stream>>>(scores);
    // V^T[b] = Wv·x[b]^T + bv(row)   [8][4096,1024]  (into dead Q region)
    gemm_nt<2,0,0,0><<<dim3(8,32,8), 256, 0, stream>>>(Wvb,0, xb,524288, bv, nullptr,0, VTb,4194304, 512,512,1024, 512, 1.0f);
    // sdpa[b] = attn[b]·(V^T[b])^T   [8][1024,4096]  (into dead K region)
    gemm_nt<0,0,0,0><<<dim3(32,8,8), 256, 0, stream>>>(attnb,2097152, VTb,4194304, nullptr, nullptr,0, sdpab,4194304, 2048,1024,4096, 1024, 1.0f);
    // hsum = sdpa·Wo^T + bo + x   f32 [8192,512]  (into dead VT region)
    gemm_nt<1,0,1,1><<<dim3(4,64,1), 256, 0, stream>>>(sdpab,0, Wob,0, bo, x,0, hsum,0, 4096,4096,512, 4096, 1.0f);
    // h = LN(hsum) -> f32 + bf16
    k_layernorm<<<2048, 256, 0, stream>>>(hsum, g0, be0, hf, hb);
    // ff1 = relu(h·W1^T + b1) bf16
    gemm_nt<1,1,0,0><<<dim3(4,64,1), 256, 0, stream>>>(hb,0, W1b,0, b1, nullptr,0, ff1b,0, 512,512,512, 512, 1.0f);
    // t2 = ff1·W2^T + b2 + h  f32
    gemm_nt<1,0,1,1><<<dim3(4,64,1), 256, 0, stream>>>(ff1b,0, W2b,0, b2, hf,0, t2,0, 512,512,512, 512, 1.0f);
    // out = LN(t2)
    k_layernorm<<<2048, 256, 0, stream>>>(t2, g1, be1, out, nullptr);
}

// Round 3
// 751.541 us; speedup vs baseline: 1.0951x; 1.0951x over previous
//
#include <hip/hip_runtime.h>

typedef unsigned short u16;
typedef unsigned int u32;
typedef float f32x4 __attribute__((ext_vector_type(4)));
typedef __bf16 bf16x8 __attribute__((ext_vector_type(8)));

__device__ __forceinline__ u16 f2b(float f) {
    u32 b = __builtin_bit_cast(u32, f);
    b = b + 0x7FFFu + ((b >> 16) & 1u);
    return (u16)(b >> 16);
}

// ---------------- fp32 -> bf16 convert (4 elems/thread) ----------------
__global__ __launch_bounds__(256) void k_convert(const float* __restrict__ in,
                                                 u16* __restrict__ out, int n4) {
    int i = blockIdx.x * 256 + threadIdx.x;
    if (i >= n4) return;
    f32x4 v = reinterpret_cast<const f32x4*>(in)[i];
    ushort4 o;
    o.x = f2b(v.x); o.y = f2b(v.y); o.z = f2b(v.z); o.w = f2b(v.w);
    reinterpret_cast<ushort4*>(out)[i] = o;
}

// ---------------- generic NT bf16 GEMM (global_load_lds staging, m97 structure) ----------------
// C[m,n] = scale * sum_k A[m,k]*B[n,k]  (+bias)(+relu)(+res), A,B bf16(u16), out f32 or bf16
// BM=BN=128, BK=64, 256 threads (4 waves, 2x2 of 64x64), mfma 16x16x32 bf16.
// LDS fragment-ordered: slot s = mt*2+ks (16 slots x 1KB per matrix); within slot, lane-major 16B.
// Fragment (A and B identical): lane l -> row = mt*16 + (l&15), k = ks*32 + (l>>4)*8 + j.
// Staging: wave w loads slots s=w*4+q via global_load_lds(16B): LDS dest linear (base+lane*16),
// global src pre-swizzled per-lane: row = m0 + w*32 + (q>>1)*16 + (l&15), k = k0 + (q&1)*32 + (l>>4)*8.
template<int BIAS /*0 none,1 col,2 row*/, int ACT, int OUTF32, int RES>
__global__ __launch_bounds__(256, 2) void gemm_nt(
    const u16* __restrict__ A, long sA,
    const u16* __restrict__ B, long sB,
    const float* __restrict__ bias,
    const float* __restrict__ res, long sRes,
    void* __restrict__ Cv, long sC,
    int ldA, int ldB, int ldC, int K, float scale)
{
    __shared__ u16 Al[8192];
    __shared__ u16 Bl[8192];
    const int tid = threadIdx.x;
    const int bz = blockIdx.z;
    const int m0 = blockIdx.y * 128;
    const int n0 = blockIdx.x * 128;
    A += (long)bz * sA;
    B += (long)bz * sB;
    const int l = tid & 63;
    const int w = tid >> 6;
    const int wr = w >> 1, wc = w & 1;

    // per-lane pre-swizzled global base (fragment-order source)
    const int fr = l & 15;        // row within 16-row fragment
    const int fk = (l >> 4) * 8;  // k offset within 32-wide k-slice
    const u16* gA = A + (long)(m0 + w * 32 + fr) * ldA + fk;
    const u16* gB = B + (long)(n0 + w * 32 + fr) * ldB + fk;
    u16* lA = &Al[w * 2048];      // wave's 4 A slots (4 x 512 u16)
    u16* lB = &Bl[w * 2048];

    f32x4 acc[4][4] = {};

    for (int k0 = 0; k0 < K; k0 += 64) {
        __syncthreads();  // previous iter's LDS reads done before overwrite
        #pragma unroll
        for (int q = 0; q < 4; q++) {
            const long ka = k0 + (q & 1) * 32 + (long)(q >> 1) * 16 * ldA;
            const long kb = k0 + (q & 1) * 32 + (long)(q >> 1) * 16 * ldB;
            __builtin_amdgcn_global_load_lds(
                (const __attribute__((address_space(1))) u32*)(gA + ka),
                (__attribute__((address_space(3))) u32*)(lA + q * 512), 16, 0, 0);
            __builtin_amdgcn_global_load_lds(
                (const __attribute__((address_space(1))) u32*)(gB + kb),
                (__attribute__((address_space(3))) u32*)(lB + q * 512), 16, 0, 0);
        }
        __syncthreads();  // compiler drains vmcnt(0) before barrier -> LDS tile ready
        #pragma unroll
        for (int ks = 0; ks < 2; ks++) {
            bf16x8 af[4], bfr[4];
            #pragma unroll
            for (int t = 0; t < 4; t++) {
                af[t]  = *reinterpret_cast<const bf16x8*>(&Al[((wr * 4 + t) * 2 + ks) * 512 + l * 8]);
                bfr[t] = *reinterpret_cast<const bf16x8*>(&Bl[((wc * 4 + t) * 2 + ks) * 512 + l * 8]);
            }
            #pragma unroll
            for (int mt = 0; mt < 4; mt++)
                #pragma unroll
                for (int nt = 0; nt < 4; nt++)
                    acc[mt][nt] = __builtin_amdgcn_mfma_f32_16x16x32_bf16(af[mt], bfr[nt], acc[mt][nt], 0, 0, 0);
        }
    }

    // epilogue: D col=l&15, row=(l>>4)*4+reg (m89-verified layout)
    const int lr = (l >> 4) * 4;
    const int lc = l & 15;
    #pragma unroll
    for (int mt = 0; mt < 4; mt++) {
        #pragma unroll
        for (int i = 0; i < 4; i++) {
            const int row = m0 + wr * 64 + mt * 16 + lr + i;
            #pragma unroll
            for (int nt = 0; nt < 4; nt++) {
                const int col = n0 + wc * 64 + nt * 16 + lc;
                float v = acc[mt][nt][i] * scale;
                if (BIAS == 1) v += bias[col];
                if (BIAS == 2) v += bias[row];
                if (ACT) v = fmaxf(v, 0.0f);
                if (RES) v += res[(long)bz * sRes + (long)row * ldC + col];
                const long ci = (long)bz * sC + (long)row * ldC + col;
                if (OUTF32) ((float*)Cv)[ci] = v;
                else        ((u16*)Cv)[ci] = f2b(v);
            }
        }
    }
}

// ------- row softmax: 1024 f32 in -> 1024 bf16 written IN-PLACE (row stride 2048 u16) -------
__global__ __launch_bounds__(256) void k_softmax(float* __restrict__ sc) {
    __shared__ float red[8];
    const int r = blockIdx.x;
    const int t = threadIdx.x;
    const int w = t >> 6;
    float* p = sc + (long)r * 1024;
    f32x4 v = reinterpret_cast<const f32x4*>(p)[t];
    float m = fmaxf(fmaxf(v.x, v.y), fmaxf(v.z, v.w));
    #pragma unroll
    for (int d = 32; d >= 1; d >>= 1) m = fmaxf(m, __shfl_xor(m, d));
    if ((t & 63) == 0) red[w] = m;
    __syncthreads();
    m = fmaxf(fmaxf(red[0], red[1]), fmaxf(red[2], red[3]));
    f32x4 e;
    e.x = __expf(v.x - m); e.y = __expf(v.y - m);
    e.z = __expf(v.z - m); e.w = __expf(v.w - m);
    float s = e.x + e.y + e.z + e.w;
    #pragma unroll
    for (int d = 32; d >= 1; d >>= 1) s += __shfl_xor(s, d);
    if ((t & 63) == 0) red[4 + w] = s;
    __syncthreads();
    s = red[4] + red[5] + red[6] + red[7];
    const float inv = 1.0f / s;
    ushort4 o;
    o.x = f2b(e.x * inv); o.y = f2b(e.y * inv);
    o.z = f2b(e.z * inv); o.w = f2b(e.w * inv);
    // write bf16 attn row into the first 2KB of this row's own 4KB slot (no cross-row overlap)
    reinterpret_cast<ushort4*>(reinterpret_cast<u16*>(sc) + (long)r * 2048)[t] = o;
}

// ---------------- LayerNorm over D=512, one wave per row ----------------
__global__ __launch_bounds__(256) void k_layernorm(const float* __restrict__ in,
                                                   const float* __restrict__ g,
                                                   const float* __restrict__ be,
                                                   float* __restrict__ of,
                                                   u16* __restrict__ ob) {
    const int w = threadIdx.x >> 6;
    const int l = threadIdx.x & 63;
    const long row = (long)blockIdx.x * 4 + w;
    const float* p = in + row * 512;
    f32x4 v0 = *reinterpret_cast<const f32x4*>(p + l * 4);
    f32x4 v1 = *reinterpret_cast<const f32x4*>(p + 256 + l * 4);
    float s = v0.x + v0.y + v0.z + v0.w + v1.x + v1.y + v1.z + v1.w;
    float q = v0.x * v0.x + v0.y * v0.y + v0.z * v0.z + v0.w * v0.w
            + v1.x * v1.x + v1.y * v1.y + v1.z * v1.z + v1.w * v1.w;
    #pragma unroll
    for (int d = 32; d >= 1; d >>= 1) { s += __shfl_xor(s, d); q += __shfl_xor(q, d); }
    const float mean = s * (1.0f / 512.0f);
    const float var = q * (1.0f / 512.0f) - mean * mean;
    const float inv = rsqrtf(var + 1e-5f);
    f32x4 ga = *reinterpret_cast<const f32x4*>(g + l * 4);
    f32x4 gb = *reinterpret_cast<const f32x4*>(g + 256 + l * 4);
    f32x4 ba = *reinterpret_cast<const f32x4*>(be + l * 4);
    f32x4 bb = *reinterpret_cast<const f32x4*>(be + 256 + l * 4);
    f32x4 o0 = (v0 - mean) * inv * ga + ba;
    f32x4 o1 = (v1 - mean) * inv * gb + bb;
    *reinterpret_cast<f32x4*>(of + row * 512 + l * 4) = o0;
    *reinterpret_cast<f32x4*>(of + row * 512 + 256 + l * 4) = o1;
    if (ob) {
        ushort4 p0, p1;
        p0.x = f2b(o0.x); p0.y = f2b(o0.y); p0.z = f2b(o0.z); p0.w = f2b(o0.w);
        p1.x = f2b(o1.x); p1.y = f2b(o1.y); p1.z = f2b(o1.z); p1.w = f2b(o1.w);
        *reinterpret_cast<ushort4*>(ob + row * 512 + l * 4) = p0;
        *reinterpret_cast<ushort4*>(ob + row * 512 + 256 + l * 4) = p1;
    }
}

extern "C" void kernel_launch(void* const* d_in, const int* in_sizes, int n_in,
                              void* d_out, int out_size, void* d_ws, size_t ws_size,
                              hipStream_t stream) {
    const float* x   = (const float*)d_in[0];
    const float* Wq  = (const float*)d_in[1];
    const float* bq  = (const float*)d_in[2];
    const float* Wk  = (const float*)d_in[3];
    const float* bk  = (const float*)d_in[4];
    const float* Wv  = (const float*)d_in[5];
    const float* bv  = (const float*)d_in[6];
    const float* Wo  = (const float*)d_in[7];
    const float* bo  = (const float*)d_in[8];
    const float* g0  = (const float*)d_in[9];
    const float* be0 = (const float*)d_in[10];
    const float* W1  = (const float*)d_in[11];
    const float* b1  = (const float*)d_in[12];
    const float* W2  = (const float*)d_in[13];
    const float* b2  = (const float*)d_in[14];
    const float* g1  = (const float*)d_in[15];
    const float* be1 = (const float*)d_in[16];
    float* out = (float*)d_out;

    // ---- workspace layout, peak 194.0 MB ----
    char* ws = (char*)d_ws;
    u16*   xb     = (u16*)(ws + 0);            // [8192,512] bf16, 8.4 MB
    u16*   Wqb    = (u16*)(ws + 8388608);      // 4 MB each
    u16*   Wkb    = (u16*)(ws + 12582912);
    u16*   Wvb    = (u16*)(ws + 16777216);
    u16*   Wob    = (u16*)(ws + 20971520);
    u16*   W1b    = (u16*)(ws + 25165824);
    u16*   W2b    = (u16*)(ws + 25690112);
    // region R1 [26214400 .. 93323264): Q -> later VT -> later hsum/hf/hb/ff1/t2
    u16*   Qb     = (u16*)(ws + 26214400);     // [8192,4096] bf16
    u16*   VTb    = Qb;                        // [8][4096,1024] bf16 (Q dead after scores)
    float* hsum   = (float*)(ws + 26214400);   // [8192,512] f32 (VT dead after PV)
    float* hf     = (float*)(ws + 42991616);
    u16*   hb     = (u16*)(ws + 59768832);
    u16*   ff1b   = (u16*)(ws + 68157440);
    float* t2     = (float*)(ws + 76546048);   // ends exactly at 93323264
    // region R2 [93323264 .. 160432128): K -> later sdpa
    u16*   Kb     = (u16*)(ws + 93323264);     // [8192,4096] bf16
    u16*   sdpab  = Kb;                        // [8][1024,4096] bf16 (K dead after scores)
    // region R3 [160432128 .. 193986560): scores f32, attn bf16 in-place (ld 2048)
    float* scores = (float*)(ws + 160432128);  // [8,1024,1024] f32
    u16*   attnb  = (u16*)scores;              // rows at stride 2048 u16

    // bf16 conversions
    k_convert<<<4096, 256, 0, stream>>>(x,  xb,  1048576);
    k_convert<<<2048, 256, 0, stream>>>(Wq, Wqb, 524288);
    k_convert<<<2048, 256, 0, stream>>>(Wk, Wkb, 524288);
    k_convert<<<2048, 256, 0, stream>>>(Wv, Wvb, 524288);
    k_convert<<<2048, 256, 0, stream>>>(Wo, Wob, 524288);
    k_convert<<<256,  256, 0, stream>>>(W1, W1b, 65536);
    k_convert<<<256,  256, 0, stream>>>(W2, W2b, 65536);

    const float scl = 0.044194173824159216f; // 1/sqrt(512)

    // Q = x·Wq^T + bq   [8192,4096]
    gemm_nt<1,0,0,0><<<dim3(32,64,1), 256, 0, stream>>>(xb,0, Wqb,0, bq, nullptr,0, Qb,0, 512,512,4096, 512, 1.0f);
    // K = x·Wk^T + bk
    gemm_nt<1,0,0,0><<<dim3(32,64,1), 256, 0, stream>>>(xb,0, Wkb,0, bk, nullptr,0, Kb,0, 512,512,4096, 512, 1.0f);
    // scores[b] = (Q[b]·K[b]^T)/sqrt(512)  f32 [8][1024,1024]
    gemm_nt<0,0,1,0><<<dim3(8,8,8), 256, 0, stream>>>(Qb,4194304, Kb,4194304, nullptr, nullptr,0, scores,1048576, 4096,4096,1024, 4096, scl);
    // attn = softmax(scores) -> bf16 in-place (row stride 2048)
    k_softmax<<<8192, 256, 0, stream>>>(scores);
    // V^T[b] = Wv·x[b]^T + bv(row)   [8][4096,1024]  (into dead Q region)
    gemm_nt<2,0,0,0><<<dim3(8,32,8), 256, 0, stream>>>(Wvb,0, xb,524288, bv, nullptr,0, VTb,4194304, 512,512,1024, 512, 1.0f);
    // sdpa[b] = attn[b]·(V^T[b])^T   [8][1024,4096]  (into dead K region)
    gemm_nt<0,0,0,0><<<dim3(32,8,8), 256, 0, stream>>>(attnb,2097152, VTb,4194304, nullptr, nullptr,0, sdpab,4194304, 2048,1024,4096, 1024, 1.0f);
    // hsum = sdpa·Wo^T + bo + x   f32 [8192,512]  (into dead VT region)
    gemm_nt<1,0,1,1><<<dim3(4,64,1), 256, 0, stream>>>(sdpab,0, Wob,0, bo, x,0, hsum,0, 4096,4096,512, 4096, 1.0f);
    // h = LN(hsum) -> f32 + bf16
    k_layernorm<<<2048, 256, 0, stream>>>(hsum, g0, be0, hf, hb);
    // ff1 = relu(h·W1^T + b1) bf16
    gemm_nt<1,1,0,0><<<dim3(4,64,1), 256, 0, stream>>>(hb,0, W1b,0, b1, nullptr,0, ff1b,0, 512,512,512, 512, 1.0f);
    // t2 = ff1·W2^T + b2 + h  f32
    gemm_nt<1,0,1,1><<<dim3(4,64,1), 256, 0, stream>>>(ff1b,0, W2b,0, b2, hf,0, t2,0, 512,512,512, 512, 1.0f);
    // out = LN(t2)
    k_layernorm<<<2048, 256, 0, stream>>>(t2, g1, be1, out, nullptr);
}